// Round 1
// baseline (550.939 us; speedup 1.0000x reference)
//
#include <hip/hip_runtime.h>
#include <math.h>

// Problem constants (fixed by setup_inputs)
#define BB 2
#define TT 5
#define HH 64
#define WW 2048
#define NPTS 4096
#define NBT (BB * TT)
#define NELEM (BB * TT * HH * WW)   // 1,310,720

// ws layout (floats): [0]=sum_rv, [1]=sum_mask, [2..12)=cd1 sums, [12..22)=cd2 sums
#define WS_FLOATS 22

__global__ void init_kernel(float* ws) {
    int i = threadIdx.x;
    if (i < WS_FLOATS) ws[i] = 0.0f;
}

// Elementwise: L1 range loss + BCE-with-logits mask loss, float4-vectorized.
__global__ void ew_kernel(const float4* __restrict__ rv,
                          const float4* __restrict__ logits,
                          const float4* __restrict__ tgt,
                          float* __restrict__ sums, int n4) {
    int idx = blockIdx.x * blockDim.x + threadIdx.x;
    int stride = gridDim.x * blockDim.x;
    float srv = 0.0f, smk = 0.0f;
    for (int i = idx; i < n4; i += stride) {
        float4 o4 = rv[i];
        float4 x4 = logits[i];
        float4 t4 = tgt[i];
        const float* op = &o4.x;
        const float* xp = &x4.x;
        const float* tp = &t4.x;
#pragma unroll
        for (int j = 0; j < 4; ++j) {
            float tv = tp[j];
            float ov = (tv == -1.0f) ? -1.0f : op[j];
            srv += fabsf(ov - tv);
            float tm = (tv > 0.0f) ? 1.0f : 0.0f;
            float xv = xp[j];
            smk += fmaxf(xv, 0.0f) - xv * tm + log1pf(expf(-fabsf(xv)));
        }
    }
    // wave reduce (64 lanes)
#pragma unroll
    for (int off = 32; off > 0; off >>= 1) {
        srv += __shfl_down(srv, off);
        smk += __shfl_down(smk, off);
    }
    __shared__ float s1[4], s2[4];
    int lane = threadIdx.x & 63;
    int wid = threadIdx.x >> 6;
    if (lane == 0) { s1[wid] = srv; s2[wid] = smk; }
    __syncthreads();
    if (threadIdx.x == 0) {
        float a = 0.0f, b = 0.0f;
#pragma unroll
        for (int w = 0; w < 4; ++w) { a += s1[w]; b += s2[w]; }
        atomicAdd(&sums[0], a);
        atomicAdd(&sums[1], b);
    }
}

// One direction of chamfer: for each query point in P, min squared dist to all
// of Q (same (b,t)); block-sum of mins -> atomicAdd(sums[bt]).
#define CTILE 512
__global__ void chamfer_kernel(const float* __restrict__ P,
                               const float* __restrict__ Q,
                               float* __restrict__ sums) {
    const int chunks = NPTS / 256;             // 16
    int bt = blockIdx.x / chunks;
    int chunk = blockIdx.x % chunks;
    const float* Pb = P + (size_t)bt * NPTS * 3;
    const float* Qb = Q + (size_t)bt * NPTS * 3;

    int n = chunk * 256 + threadIdx.x;
    float px = Pb[n * 3 + 0];
    float py = Pb[n * 3 + 1];
    float pz = Pb[n * 3 + 2];

    __shared__ float qs[CTILE * 3];
    float dmin = INFINITY;
    for (int m0 = 0; m0 < NPTS; m0 += CTILE) {
        for (int j = threadIdx.x; j < CTILE * 3; j += 256)
            qs[j] = Qb[m0 * 3 + j];
        __syncthreads();
#pragma unroll 8
        for (int m = 0; m < CTILE; ++m) {
            float dx = px - qs[m * 3 + 0];
            float dy = py - qs[m * 3 + 1];
            float dz = pz - qs[m * 3 + 2];
            float d = fmaf(dx, dx, fmaf(dy, dy, dz * dz));
            dmin = fminf(dmin, d);
        }
        __syncthreads();
    }
    // block-reduce sum of dmin
    float s = dmin;
#pragma unroll
    for (int off = 32; off > 0; off >>= 1) s += __shfl_down(s, off);
    __shared__ float sred[4];
    int lane = threadIdx.x & 63;
    int wid = threadIdx.x >> 6;
    if (lane == 0) sred[wid] = s;
    __syncthreads();
    if (threadIdx.x == 0) {
        float tot = sred[0] + sred[1] + sred[2] + sred[3];
        atomicAdd(&sums[bt], tot);
    }
}

__global__ void finalize_kernel(const float* __restrict__ ws, float* __restrict__ out) {
    if (threadIdx.x == 0) {
        const float inv_e = 1.0f / (float)NELEM;
        float loss_rv = ws[0] * inv_e;
        float loss_mask = ws[1] * inv_e;
        float cd_sum = 0.0f;
        for (int bt = 0; bt < NBT; ++bt) {
            float cd = ws[2 + bt] * (1.0f / NPTS) + ws[12 + bt] * (1.0f / NPTS);
            int b = bt / TT;
            int t = bt % TT;
            out[1 + t * BB + b] = cd;   // cd_tensor is [T,B]
            cd_sum += cd;
        }
        float loss_cd = cd_sum / (float)NBT;
        out[0] = loss_cd + loss_rv + loss_mask;  // weights all 1.0
        out[11] = loss_cd;
        out[12] = loss_rv;
        out[13] = loss_mask;
    }
}

extern "C" void kernel_launch(void* const* d_in, const int* in_sizes, int n_in,
                              void* d_out, int out_size, void* d_ws, size_t ws_size,
                              hipStream_t stream) {
    const float* output_rv = (const float*)d_in[0];
    const float* mask_logits = (const float*)d_in[1];
    const float* output_points = (const float*)d_in[2];
    const float* target_points = (const float*)d_in[3];
    const float* target_rv = (const float*)d_in[4];
    float* out = (float*)d_out;
    float* ws = (float*)d_ws;

    init_kernel<<<1, 64, 0, stream>>>(ws);

    int n4 = NELEM / 4;
    ew_kernel<<<1280, 256, 0, stream>>>((const float4*)output_rv,
                                        (const float4*)mask_logits,
                                        (const float4*)target_rv, ws, n4);

    // dist1: out->tgt ; dist2: tgt->out
    chamfer_kernel<<<NBT * (NPTS / 256), 256, 0, stream>>>(output_points, target_points, ws + 2);
    chamfer_kernel<<<NBT * (NPTS / 256), 256, 0, stream>>>(target_points, output_points, ws + 12);

    finalize_kernel<<<1, 64, 0, stream>>>(ws, out);
}

// Round 3
// 78.638 us; speedup vs baseline: 7.0060x; 7.0060x over previous
//
#include <hip/hip_runtime.h>
#include <math.h>

// Problem constants (fixed by setup_inputs)
#define BB 2
#define TT 5
#define HH 64
#define WW 2048
#define NPTS 4096
#define NBT (BB * TT)
#define NELEM (BB * TT * HH * WW)   // 1,310,720

// ws layout (floats): [0]=sum_rv, [1]=sum_mask, [2..12)=cd dir0 sums, [12..22)=cd dir1 sums
#define WS_FLOATS 22

__global__ void init_kernel(float* ws) {
    int i = threadIdx.x;
    if (i < WS_FLOATS) ws[i] = 0.0f;
}

// Elementwise: L1 range loss + BCE-with-logits mask loss, float4-vectorized.
__global__ void ew_kernel(const float4* __restrict__ rv,
                          const float4* __restrict__ logits,
                          const float4* __restrict__ tgt,
                          float* __restrict__ sums, int n4) {
    int idx = blockIdx.x * blockDim.x + threadIdx.x;
    int stride = gridDim.x * blockDim.x;
    float srv = 0.0f, smk = 0.0f;
    for (int i = idx; i < n4; i += stride) {
        float4 o4 = rv[i];
        float4 x4 = logits[i];
        float4 t4 = tgt[i];
        const float* op = &o4.x;
        const float* xp = &x4.x;
        const float* tp = &t4.x;
#pragma unroll
        for (int j = 0; j < 4; ++j) {
            float tv = tp[j];
            float ov = (tv == -1.0f) ? -1.0f : op[j];
            srv += fabsf(ov - tv);
            float tm = (tv > 0.0f) ? 1.0f : 0.0f;
            float xv = xp[j];
            smk += fmaxf(xv, 0.0f) - xv * tm + log1pf(expf(-fabsf(xv)));
        }
    }
#pragma unroll
    for (int off = 32; off > 0; off >>= 1) {
        srv += __shfl_down(srv, off);
        smk += __shfl_down(smk, off);
    }
    __shared__ float s1[4], s2[4];
    int lane = threadIdx.x & 63;
    int wid = threadIdx.x >> 6;
    if (lane == 0) { s1[wid] = srv; s2[wid] = smk; }
    __syncthreads();
    if (threadIdx.x == 0) {
        float a = 0.0f, b = 0.0f;
#pragma unroll
        for (int w = 0; w < 4; ++w) { a += s1[w]; b += s2[w]; }
        atomicAdd(&sums[0], a);
        atomicAdd(&sums[1], b);
    }
}

// Both chamfer directions in one launch.
// Per query point: min over d2 = ||p||^2 + (||q||^2 - 2 p.q); we track
// min of val = ||q||^2 - 2 p.q (3 fma + 1 min per pair from LDS-prepped
// float4(-2q, ||q||^2)) and add ||p||^2 once at the end.
// PP=16 lanes share one query group (interleaved m), RQ=4 queries/thread.
#define PP 16
#define RQ 4
#define QB 64                 // queries per block = (256/PP)*RQ
#define CT 512                // staged tile (points)
#define NQCHUNK (NPTS / QB)   // 64
#define BLKS_PER_DIR (NBT * NQCHUNK)  // 640

__global__ __launch_bounds__(256) void chamfer_kernel(
        const float* __restrict__ OP,   // output_points
        const float* __restrict__ TP,   // target_points
        float* __restrict__ sums) {     // [0..10)=dir0 (out->tgt), [10..20)=dir1
    int bid = blockIdx.x;
    int dir = bid / BLKS_PER_DIR;
    int rem = bid % BLKS_PER_DIR;
    int bt = rem / NQCHUNK;
    int qchunk = rem % NQCHUNK;
    const float* P = (dir == 0) ? OP : TP;
    const float* Q = (dir == 0) ? TP : OP;
    const float* Pb = P + (size_t)bt * NPTS * 3;
    const float* Qb = Q + (size_t)bt * NPTS * 3;

    int tid = threadIdx.x;
    int part = tid & (PP - 1);
    int qg = tid >> 4;                 // 16 query-groups per block
    int n0 = qchunk * QB + qg * RQ;

    float px[RQ], py[RQ], pz[RQ], pn[RQ], vmin[RQ];
#pragma unroll
    for (int i = 0; i < RQ; ++i) {
        float x = Pb[(n0 + i) * 3 + 0];
        float y = Pb[(n0 + i) * 3 + 1];
        float z = Pb[(n0 + i) * 3 + 2];
        px[i] = x; py[i] = y; pz[i] = z;
        pn[i] = fmaf(x, x, fmaf(y, y, z * z));
        vmin[i] = INFINITY;
    }

    __shared__ float4 qs[2][CT];

    // stage tile t into buffer buf: 2 points per thread
#define STAGE(t, buf)                                                   \
    {                                                                   \
        int m0 = (t) * CT;                                              \
        _Pragma("unroll")                                               \
        for (int i = 0; i < 2; ++i) {                                   \
            int j = tid * 2 + i;                                        \
            const float* q = Qb + (size_t)(m0 + j) * 3;                 \
            float x = q[0], y = q[1], z = q[2];                         \
            qs[buf][j] = make_float4(-2.0f * x, -2.0f * y, -2.0f * z,   \
                                     fmaf(x, x, fmaf(y, y, z * z)));    \
        }                                                               \
    }

    const int NT = NPTS / CT;   // 8
    STAGE(0, 0);
    for (int t = 0; t < NT; ++t) {
        __syncthreads();
        if (t + 1 < NT) STAGE(t + 1, (t + 1) & 1);
        const float4* qb = qs[t & 1];
#pragma unroll 4
        for (int k = 0; k < CT / PP; ++k) {   // 32 iters
            float4 v = qb[part + k * PP];
#pragma unroll
            for (int i = 0; i < RQ; ++i) {
                float d = fmaf(px[i], v.x, fmaf(py[i], v.y, fmaf(pz[i], v.z, v.w)));
                vmin[i] = fminf(vmin[i], d);
            }
        }
    }

    // combine the 16 parts of each query (lanes qg*16 .. qg*16+15)
#pragma unroll
    for (int i = 0; i < RQ; ++i) {
        vmin[i] = fminf(vmin[i], __shfl_xor(vmin[i], 1));
        vmin[i] = fminf(vmin[i], __shfl_xor(vmin[i], 2));
        vmin[i] = fminf(vmin[i], __shfl_xor(vmin[i], 4));
        vmin[i] = fminf(vmin[i], __shfl_xor(vmin[i], 8));
    }
    float s = 0.0f;
    if (part == 0) {
#pragma unroll
        for (int i = 0; i < RQ; ++i) s += vmin[i] + pn[i];
    }
#pragma unroll
    for (int off = 32; off > 0; off >>= 1) s += __shfl_down(s, off);
    __shared__ float sred[4];
    if ((tid & 63) == 0) sred[tid >> 6] = s;
    __syncthreads();
    if (tid == 0)
        atomicAdd(&sums[dir * NBT + bt], sred[0] + sred[1] + sred[2] + sred[3]);
}

__global__ void finalize_kernel(const float* __restrict__ ws, float* __restrict__ out) {
    if (threadIdx.x == 0) {
        const float inv_e = 1.0f / (float)NELEM;
        float loss_rv = ws[0] * inv_e;
        float loss_mask = ws[1] * inv_e;
        float cd_sum = 0.0f;
        for (int bt = 0; bt < NBT; ++bt) {
            float cd = ws[2 + bt] * (1.0f / NPTS) + ws[12 + bt] * (1.0f / NPTS);
            int b = bt / TT;
            int t = bt % TT;
            out[1 + t * BB + b] = cd;   // cd_tensor is [T,B]
            cd_sum += cd;
        }
        float loss_cd = cd_sum / (float)NBT;
        out[0] = loss_cd + loss_rv + loss_mask;  // weights all 1.0
        out[11] = loss_cd;
        out[12] = loss_rv;
        out[13] = loss_mask;
    }
}

extern "C" void kernel_launch(void* const* d_in, const int* in_sizes, int n_in,
                              void* d_out, int out_size, void* d_ws, size_t ws_size,
                              hipStream_t stream) {
    const float* output_rv = (const float*)d_in[0];
    const float* mask_logits = (const float*)d_in[1];
    const float* output_points = (const float*)d_in[2];
    const float* target_points = (const float*)d_in[3];
    const float* target_rv = (const float*)d_in[4];
    float* out = (float*)d_out;
    float* ws = (float*)d_ws;

    init_kernel<<<1, 64, 0, stream>>>(ws);

    int n4 = NELEM / 4;
    ew_kernel<<<1280, 256, 0, stream>>>((const float4*)output_rv,
                                        (const float4*)mask_logits,
                                        (const float4*)target_rv, ws, n4);

    chamfer_kernel<<<2 * BLKS_PER_DIR, 256, 0, stream>>>(output_points, target_points, ws + 2);

    finalize_kernel<<<1, 64, 0, stream>>>(ws, out);
}

// Round 7
// 49.406 us; speedup vs baseline: 11.1513x; 1.5917x over previous
//
#include <hip/hip_runtime.h>
#include <math.h>

// Problem constants (fixed by setup_inputs)
#define BB 2
#define TT 5
#define NPTS 4096
#define NBT (BB * TT)
#define NELEM (BB * TT * 64 * 2048)   // 1,310,720

// Main kernel block-role split
#define EW_BLOCKS 640                 // elementwise losses
#define RQ 16                         // queries per wave (SGPR-resident)
#define QB 64                         // queries per block (4 waves * RQ)
#define NQCHUNK (NPTS / QB)           // 64
#define CH_BLOCKS (2 * NBT * NQCHUNK) // 1280
#define CT 512                        // staged tile (points)

// ws layout (floats):
//   [0..640)        ew srv partials (per ew block)
//   [640..1280)     ew smk partials
//   [1280..2560)    chamfer partials, slot = 1280 + dir*640 + bt*64 + qchunk
#define CH_WS 1280

__device__ inline float rfl(float x) {
    return __int_as_float(__builtin_amdgcn_readfirstlane(__float_as_int(x)));
}

__global__ __launch_bounds__(256) void main_kernel(
        const float4* __restrict__ rv4,
        const float4* __restrict__ lg4,
        const float4* __restrict__ tg4,
        const float* __restrict__ OP,
        const float* __restrict__ TP,
        float* __restrict__ ws) {
    __shared__ float4 qs[2][CT];
    __shared__ float sred[4];
    int bid = blockIdx.x;
    int tid = threadIdx.x;
    int lane = tid & 63;
    int wave = tid >> 6;

    if (bid < EW_BLOCKS) {
        // ---------------- elementwise: L1 range + BCE mask ----------------
        float srv = 0.0f, smk = 0.0f;
        int base = (bid * 256 + tid) * 2;
#pragma unroll
        for (int u = 0; u < 2; ++u) {
            int i = base + u;
            float4 o4 = rv4[i];
            float4 x4 = lg4[i];
            float4 t4 = tg4[i];
            const float* op = &o4.x;
            const float* xp = &x4.x;
            const float* tp = &t4.x;
#pragma unroll
            for (int j = 0; j < 4; ++j) {
                float tv = tp[j];
                float ov = (tv == -1.0f) ? -1.0f : op[j];
                srv += fabsf(ov - tv);
                float tm = (tv > 0.0f) ? 1.0f : 0.0f;
                float xv = xp[j];
                smk += fmaxf(xv, 0.0f) - xv * tm + log1pf(expf(-fabsf(xv)));
            }
        }
#pragma unroll
        for (int off = 32; off > 0; off >>= 1) {
            srv += __shfl_down(srv, off);
            smk += __shfl_down(smk, off);
        }
        __shared__ float s1[4], s2[4];
        if (lane == 0) { s1[wave] = srv; s2[wave] = smk; }
        __syncthreads();
        if (tid == 0) {
            ws[bid] = s1[0] + s1[1] + s1[2] + s1[3];
            ws[EW_BLOCKS + bid] = s2[0] + s2[1] + s2[2] + s2[3];
        }
        return;
    }

    // ---------------- chamfer: one direction chunk per block ----------------
    int cb = bid - EW_BLOCKS;            // 0..1280
    int dir = cb / (NBT * NQCHUNK);
    int rem = cb % (NBT * NQCHUNK);
    int bt = rem / NQCHUNK;
    int qchunk = rem % NQCHUNK;
    const float* P = dir ? TP : OP;      // queries
    const float* Q = dir ? OP : TP;      // references
    const float* Pb = P + (size_t)bt * NPTS * 3;
    const float* Qb = Q + (size_t)bt * NPTS * 3;

    // Load this wave's RQ=16 query points as wave-uniform scalars (SGPRs).
    int n0 = qchunk * QB + wave * RQ;
    float qx[RQ], qy[RQ], qz[RQ], pn[RQ], vmin[RQ];
#pragma unroll
    for (int i = 0; i < RQ; ++i) {
        const float* p = Pb + (size_t)(n0 + i) * 3;
        float x = rfl(p[0]);
        float y = rfl(p[1]);
        float z = rfl(p[2]);
        qx[i] = x; qy[i] = y; qz[i] = z;
        pn[i] = fmaf(x, x, fmaf(y, y, z * z));
        vmin[i] = INFINITY;
    }

    // stage tile t (CT points) prepped as (-2q, ||q||^2); 2 points per thread
#define STAGE(t, buf)                                                      \
    {                                                                      \
        int m0 = (t) * CT;                                                 \
        _Pragma("unroll")                                                  \
        for (int u = 0; u < 2; ++u) {                                      \
            int j = tid * 2 + u;                                           \
            const float* q = Qb + (size_t)(m0 + j) * 3;                    \
            float x = q[0], y = q[1], z = q[2];                            \
            qs[buf][j] = make_float4(-2.0f * x, -2.0f * y, -2.0f * z,      \
                                     fmaf(x, x, fmaf(y, y, z * z)));       \
        }                                                                  \
    }

    const int NT = NPTS / CT;   // 8
    STAGE(0, 0);
    for (int t = 0; t < NT; ++t) {
        __syncthreads();
        if (t + 1 < NT) STAGE(t + 1, (t + 1) & 1);
        const float4* qb = qs[t & 1];
#pragma unroll
        for (int k = 0; k < CT / 128; ++k) {   // 2 distinct points per lane per k
            float4 v0 = qb[k * 128 + lane];
            float4 v1 = qb[k * 128 + 64 + lane];
#pragma unroll
            for (int i = 0; i < RQ; ++i) {
                float d0 = fmaf(qx[i], v0.x, fmaf(qy[i], v0.y, fmaf(qz[i], v0.z, v0.w)));
                float d1 = fmaf(qx[i], v1.x, fmaf(qy[i], v1.y, fmaf(qz[i], v1.z, v1.w)));
                vmin[i] = fminf(vmin[i], fminf(d0, d1));   // -> v_min3_f32
            }
        }
    }

    // reduce each query's min across the 64 lanes, sum (min + ||p||^2)
    float s = 0.0f;
#pragma unroll
    for (int i = 0; i < RQ; ++i) {
        float m = vmin[i];
#pragma unroll
        for (int off = 32; off > 0; off >>= 1)
            m = fminf(m, __shfl_xor(m, off));
        s += m + pn[i];
    }
    if (lane == 0) sred[wave] = s;
    __syncthreads();
    if (tid == 0)
        ws[CH_WS + cb] = sred[0] + sred[1] + sred[2] + sred[3];
}

__global__ void finalize_kernel(const float* __restrict__ ws, float* __restrict__ out) {
    __shared__ float ra[4], rb[4];
    __shared__ float grp[32];
    int tid = threadIdx.x;
    int lane = tid & 63;
    int wave = tid >> 6;

    // ew partials: 640 each
    float sa = 0.0f, sb = 0.0f;
    for (int i = tid; i < EW_BLOCKS; i += 256) {
        sa += ws[i];
        sb += ws[EW_BLOCKS + i];
    }
#pragma unroll
    for (int off = 32; off > 0; off >>= 1) {
        sa += __shfl_down(sa, off);
        sb += __shfl_down(sb, off);
    }
    if (lane == 0) { ra[wave] = sa; rb[wave] = sb; }

    // chamfer partials: 20 groups of 64 (group g = dir*10 + bt)
    int g = tid >> 3;       // 0..31
    int o = tid & 7;
    float sg = 0.0f;
    if (g < 20)
        for (int j = o; j < NQCHUNK; j += 8)
            sg += ws[CH_WS + g * NQCHUNK + j];
    sg += __shfl_xor(sg, 1);
    sg += __shfl_xor(sg, 2);
    sg += __shfl_xor(sg, 4);
    if (o == 0 && g < 20) grp[g] = sg;
    __syncthreads();

    if (tid == 0) {
        const float inv_e = 1.0f / (float)NELEM;
        float loss_rv = (ra[0] + ra[1] + ra[2] + ra[3]) * inv_e;
        float loss_mask = (rb[0] + rb[1] + rb[2] + rb[3]) * inv_e;
        float cd_sum = 0.0f;
        for (int bt = 0; bt < NBT; ++bt) {
            float cd = (grp[bt] + grp[NBT + bt]) * (1.0f / NPTS);
            int b = bt / TT;
            int t = bt % TT;
            out[1 + t * BB + b] = cd;   // cd_tensor is [T,B]
            cd_sum += cd;
        }
        float loss_cd = cd_sum / (float)NBT;
        out[0] = loss_cd + loss_rv + loss_mask;  // weights all 1.0
        out[11] = loss_cd;
        out[12] = loss_rv;
        out[13] = loss_mask;
    }
}

extern "C" void kernel_launch(void* const* d_in, const int* in_sizes, int n_in,
                              void* d_out, int out_size, void* d_ws, size_t ws_size,
                              hipStream_t stream) {
    const float* output_rv = (const float*)d_in[0];
    const float* mask_logits = (const float*)d_in[1];
    const float* output_points = (const float*)d_in[2];
    const float* target_points = (const float*)d_in[3];
    const float* target_rv = (const float*)d_in[4];
    float* out = (float*)d_out;
    float* ws = (float*)d_ws;

    main_kernel<<<EW_BLOCKS + CH_BLOCKS, 256, 0, stream>>>(
        (const float4*)output_rv, (const float4*)mask_logits,
        (const float4*)target_rv, output_points, target_points, ws);

    finalize_kernel<<<1, 256, 0, stream>>>(ws, out);
}

// Round 8
// 34.023 us; speedup vs baseline: 16.1929x; 1.4521x over previous
//
#include <hip/hip_runtime.h>
#include <math.h>

// Problem constants (fixed by setup_inputs)
#define BB 2
#define TT 5
#define NPTS 4096
#define NBT (BB * TT)
#define NELEM (BB * TT * 64 * 2048)   // 1,310,720

// Chamfer blocks: 2 dir x 10 bt x 32 qchunks, 128 queries (4 waves x 32) each
#define CH_BLOCKS 640
#define QPB 128
#define NQC (NPTS / QPB)              // 32
#define CT 1024                       // points per staged tile (f16-packed, 8B/pt)
#define NT (NPTS / CT)                // 4
#define EW_BLOCKS 640

// ws layout (floats):
//   [0..2560)      chamfer partials, slot = cb*4 + wave  (cb = dir*320+bt*32+qc)
//   [2560..3200)   ew srv partials
//   [3200..3840)   ew smk partials
#define EW1 2560
#define EW2 3200

typedef _Float16 h8 __attribute__((ext_vector_type(8)));
typedef float f32x16 __attribute__((ext_vector_type(16)));
typedef float f32x4 __attribute__((ext_vector_type(4)));

__device__ inline unsigned pkh(float a, float b) {
    union { _Float16 h[2]; unsigned u; } c;
    c.h[0] = (_Float16)a;
    c.h[1] = (_Float16)b;
    return c.u;
}

__global__ __launch_bounds__(256) void main_kernel(
        const float4* __restrict__ rv4,
        const float4* __restrict__ lg4,
        const float4* __restrict__ tg4,
        const float* __restrict__ OP,
        const float* __restrict__ TP,
        float* __restrict__ ws) {
    __shared__ __align__(16) uint2 pts[2][CT];   // (x,y)f16, (z,n)f16 per point
    __shared__ float nqlds[4][32];
    int bid = blockIdx.x;
    int tid = threadIdx.x;
    int lane = tid & 63;
    int wave = tid >> 6;

    if (bid >= CH_BLOCKS) {
        // ---------------- elementwise: L1 range + BCE mask ----------------
        int eb = bid - CH_BLOCKS;
        float srv = 0.0f, smk = 0.0f;
        int base = (eb * 256 + tid) * 2;
#pragma unroll
        for (int u = 0; u < 2; ++u) {
            int i = base + u;
            float4 o4 = rv4[i];
            float4 x4 = lg4[i];
            float4 t4 = tg4[i];
            const float* op = &o4.x;
            const float* xp = &x4.x;
            const float* tp = &t4.x;
#pragma unroll
            for (int j = 0; j < 4; ++j) {
                float tv = tp[j];
                float ov = (tv == -1.0f) ? -1.0f : op[j];
                srv += fabsf(ov - tv);
                float tm = (tv > 0.0f) ? 1.0f : 0.0f;
                float xv = xp[j];
                // log1p(exp(-|x|)) via HW exp/log: arg in [1,2] so log() is exact enough
                smk += fmaxf(xv, 0.0f) - xv * tm + __logf(1.0f + __expf(-fabsf(xv)));
            }
        }
#pragma unroll
        for (int off = 32; off > 0; off >>= 1) {
            srv += __shfl_down(srv, off);
            smk += __shfl_down(smk, off);
        }
        __shared__ float s1[4], s2[4];
        if (lane == 0) { s1[wave] = srv; s2[wave] = smk; }
        __syncthreads();
        if (tid == 0) {
            ws[EW1 + eb] = s1[0] + s1[1] + s1[2] + s1[3];
            ws[EW2 + eb] = s2[0] + s2[1] + s2[2] + s2[3];
        }
        return;
    }

    // ---------------- chamfer via MFMA ----------------
    int dir = bid / (NBT * NQC);
    int rem = bid % (NBT * NQC);
    int bt = rem / NQC;
    int qc = rem % NQC;
    const float* P = dir ? TP : OP;      // queries
    const float* Q = dir ? OP : TP;      // references
    const float* Pb = P + (size_t)bt * NPTS * 3;
    const float* Qb = Q + (size_t)bt * NPTS * 3;

    // A fragment: row = lane&31 -> query; k=(lane>>5)*8+i; data only in k=0..3
    int qrow = lane & 31;
    int qidx = qc * QPB + wave * 32 + qrow;
    float qx = 0.0f, qy = 0.0f, qz = 0.0f;
    if (lane < 32) {
        const float* p = Pb + (size_t)qidx * 3;
        qx = p[0]; qy = p[1]; qz = p[2];
        nqlds[wave][qrow] = fmaf(qx, qx, fmaf(qy, qy, qz * qz));
    }
    union { unsigned u[4]; h8 h; } ua;
    ua.u[0] = ua.u[1] = ua.u[2] = ua.u[3] = 0u;
    if (lane < 32) {
        ua.u[0] = pkh(-2.0f * qx, -2.0f * qy);
        ua.u[1] = pkh(-2.0f * qz, 1.0f);
    }
    h8 afrag = ua.h;

    const f32x16 zc = {0.0f, 0.0f, 0.0f, 0.0f, 0.0f, 0.0f, 0.0f, 0.0f,
                       0.0f, 0.0f, 0.0f, 0.0f, 0.0f, 0.0f, 0.0f, 0.0f};
    float vm[16];
#pragma unroll
    for (int r = 0; r < 16; ++r) vm[r] = INFINITY;

    // stage tile t (CT points) as f16 (x,y | z,n); 4 points per thread
#define STAGE(t, b)                                                          \
    {                                                                        \
        int pt0 = (t) * CT + tid * 4;                                        \
        const f32x4* src = (const f32x4*)(Qb + (size_t)pt0 * 3);             \
        f32x4 c0 = src[0], c1 = src[1], c2 = src[2];                         \
        float x0 = c0[0], y0 = c0[1], z0 = c0[2];                            \
        float x1 = c0[3], y1 = c1[0], z1 = c1[1];                            \
        float x2 = c1[2], y2 = c1[3], z2 = c2[0];                            \
        float x3 = c2[1], y3 = c2[2], z3 = c2[3];                            \
        float n0 = fmaf(x0, x0, fmaf(y0, y0, z0 * z0));                      \
        float n1 = fmaf(x1, x1, fmaf(y1, y1, z1 * z1));                      \
        float n2 = fmaf(x2, x2, fmaf(y2, y2, z2 * z2));                      \
        float n3 = fmaf(x3, x3, fmaf(y3, y3, z3 * z3));                      \
        uint4* dst = (uint4*)&pts[b][tid * 4];                               \
        dst[0] = make_uint4(pkh(x0, y0), pkh(z0, n0), pkh(x1, y1), pkh(z1, n1)); \
        dst[1] = make_uint4(pkh(x2, y2), pkh(z2, n2), pkh(x3, y3), pkh(z3, n3)); \
    }

    STAGE(0, 0);
    __syncthreads();
    for (int t = 0; t < NT; ++t) {
        if (t + 1 < NT) STAGE(t + 1, (t + 1) & 1);
        const uint2* pb = pts[t & 1];
#pragma unroll 2
        for (int s = 0; s < CT / 64; ++s) {   // 2 point-subtiles of 32 per iter
            uint2 b0 = make_uint2(0u, 0u), b1 = make_uint2(0u, 0u);
            if (lane < 32) {
                b0 = pb[s * 64 + qrow];
                b1 = pb[s * 64 + 32 + qrow];
            }
            union { unsigned u[4]; h8 h; } ub0, ub1;
            ub0.u[0] = b0.x; ub0.u[1] = b0.y; ub0.u[2] = 0u; ub0.u[3] = 0u;
            ub1.u[0] = b1.x; ub1.u[1] = b1.y; ub1.u[2] = 0u; ub1.u[3] = 0u;
            f32x16 d0 = __builtin_amdgcn_mfma_f32_32x32x16_f16(afrag, ub0.h, zc, 0, 0, 0);
            f32x16 d1 = __builtin_amdgcn_mfma_f32_32x32x16_f16(afrag, ub1.h, zc, 0, 0, 0);
#pragma unroll
            for (int r = 0; r < 16; ++r) {
                float a = d0[r], c = d1[r];
                asm("v_min3_f32 %0, %0, %1, %2" : "+v"(vm[r]) : "v"(a), "v"(c));
            }
        }
        __syncthreads();
    }

    // min across the 32 lanes of each half (cols); rows live in regs
#pragma unroll
    for (int r = 0; r < 16; ++r) {
        float m = vm[r];
        m = fminf(m, __shfl_xor(m, 1));
        m = fminf(m, __shfl_xor(m, 2));
        m = fminf(m, __shfl_xor(m, 4));
        m = fminf(m, __shfl_xor(m, 8));
        m = fminf(m, __shfl_xor(m, 16));
        vm[r] = m;
    }
    float part = 0.0f;
    if ((lane & 31) == 0) {   // lanes 0 and 32 hold the 2 row-sets
        int half = lane >> 5;
#pragma unroll
        for (int r = 0; r < 16; ++r) {
            int row = (r & 3) + 8 * (r >> 2) + 4 * half;
            part += vm[r] + nqlds[wave][row];
        }
    }
    part += __shfl_xor(part, 32);
    if (lane == 0) ws[bid * 4 + wave] = part;
}

__global__ void finalize_kernel(const float* __restrict__ ws, float* __restrict__ out) {
    __shared__ float grp[20];
    __shared__ float ra[4], rb[4];
    int tid = threadIdx.x;
    int lane = tid & 63;
    int wave = tid >> 6;

    // chamfer partials: 20 groups (dir*10+bt) of 128
    for (int g = wave; g < 20; g += 4) {
        float s = 0.0f;
        for (int j = lane; j < 128; j += 64) s += ws[g * 128 + j];
#pragma unroll
        for (int off = 32; off > 0; off >>= 1) s += __shfl_down(s, off);
        if (lane == 0) grp[g] = s;
    }

    // ew partials: 640 each
    float sa = 0.0f, sb = 0.0f;
    for (int i = tid; i < EW_BLOCKS; i += 256) {
        sa += ws[EW1 + i];
        sb += ws[EW2 + i];
    }
#pragma unroll
    for (int off = 32; off > 0; off >>= 1) {
        sa += __shfl_down(sa, off);
        sb += __shfl_down(sb, off);
    }
    if (lane == 0) { ra[wave] = sa; rb[wave] = sb; }
    __syncthreads();

    if (tid == 0) {
        const float inv_e = 1.0f / (float)NELEM;
        float loss_rv = (ra[0] + ra[1] + ra[2] + ra[3]) * inv_e;
        float loss_mask = (rb[0] + rb[1] + rb[2] + rb[3]) * inv_e;
        float cd_sum = 0.0f;
        for (int bt = 0; bt < NBT; ++bt) {
            float cd = (grp[bt] + grp[NBT + bt]) * (1.0f / NPTS);
            int b = bt / TT;
            int t = bt % TT;
            out[1 + t * BB + b] = cd;   // cd_tensor is [T,B]
            cd_sum += cd;
        }
        float loss_cd = cd_sum / (float)NBT;
        out[0] = loss_cd + loss_rv + loss_mask;  // weights all 1.0
        out[11] = loss_cd;
        out[12] = loss_rv;
        out[13] = loss_mask;
    }
}

extern "C" void kernel_launch(void* const* d_in, const int* in_sizes, int n_in,
                              void* d_out, int out_size, void* d_ws, size_t ws_size,
                              hipStream_t stream) {
    const float* output_rv = (const float*)d_in[0];
    const float* mask_logits = (const float*)d_in[1];
    const float* output_points = (const float*)d_in[2];
    const float* target_points = (const float*)d_in[3];
    const float* target_rv = (const float*)d_in[4];
    float* out = (float*)d_out;
    float* ws = (float*)d_ws;

    main_kernel<<<CH_BLOCKS + EW_BLOCKS, 256, 0, stream>>>(
        (const float4*)output_rv, (const float4*)mask_logits,
        (const float4*)target_rv, output_points, target_points, ws);

    finalize_kernel<<<1, 256, 0, stream>>>(ws, out);
}

// Round 9
// 32.204 us; speedup vs baseline: 17.1080x; 1.0565x over previous
//
#include <hip/hip_runtime.h>
#include <math.h>

// Problem constants (fixed by setup_inputs)
#define BB 2
#define TT 5
#define NPTS 4096
#define NBT (BB * TT)
#define NELEM (BB * TT * 64 * 2048)   // 1,310,720

// Chamfer blocks: 2 dir x 10 bt x 32 qchunks, 128 queries (4 waves x 32) each
#define CH_BLOCKS 640
#define QPB 128
#define NQC (NPTS / QPB)              // 32
#define CT 1024                       // points per staged tile (f16-packed, 8B/pt)
#define NT (NPTS / CT)                // 4
#define EW_BLOCKS 640

// ws layout (floats):
//   [0..2560)      chamfer partials, slot = cb*4 + wave  (cb = dir*320+bt*32+qc)
//   [2560..3200)   ew srv partials
//   [3200..3840)   ew smk partials
#define EW1 2560
#define EW2 3200

typedef _Float16 h8 __attribute__((ext_vector_type(8)));
typedef float f32x16 __attribute__((ext_vector_type(16)));
typedef float f32x4 __attribute__((ext_vector_type(4)));

__device__ inline unsigned pkh(float a, float b) {
    union { _Float16 h[2]; unsigned u; } c;
    c.h[0] = (_Float16)a;
    c.h[1] = (_Float16)b;
    return c.u;
}

__global__ __launch_bounds__(256) void main_kernel(
        const float4* __restrict__ rv4,
        const float4* __restrict__ lg4,
        const float4* __restrict__ tg4,
        const float* __restrict__ OP,
        const float* __restrict__ TP,
        float* __restrict__ ws) {
    __shared__ __align__(16) uint2 pts[2][CT];   // (x,y)f16, (z,n)f16 per point
    __shared__ float nqlds[4][32];
    int bid = blockIdx.x;
    int tid = threadIdx.x;
    int lane = tid & 63;
    int wave = tid >> 6;

    if (bid >= CH_BLOCKS) {
        // ---------------- elementwise: L1 range + BCE mask ----------------
        int eb = bid - CH_BLOCKS;
        float srv = 0.0f, smk = 0.0f;
        int base = (eb * 256 + tid) * 2;
#pragma unroll
        for (int u = 0; u < 2; ++u) {
            int i = base + u;
            float4 o4 = rv4[i];
            float4 x4 = lg4[i];
            float4 t4 = tg4[i];
            const float* op = &o4.x;
            const float* xp = &x4.x;
            const float* tp = &t4.x;
#pragma unroll
            for (int j = 0; j < 4; ++j) {
                float tv = tp[j];
                float ov = (tv == -1.0f) ? -1.0f : op[j];
                srv += fabsf(ov - tv);
                float tm = (tv > 0.0f) ? 1.0f : 0.0f;
                float xv = xp[j];
                // log1p(exp(-|x|)) via HW exp/log: arg in [1,2] so log() is exact enough
                smk += fmaxf(xv, 0.0f) - xv * tm + __logf(1.0f + __expf(-fabsf(xv)));
            }
        }
#pragma unroll
        for (int off = 32; off > 0; off >>= 1) {
            srv += __shfl_down(srv, off);
            smk += __shfl_down(smk, off);
        }
        __shared__ float s1[4], s2[4];
        if (lane == 0) { s1[wave] = srv; s2[wave] = smk; }
        __syncthreads();
        if (tid == 0) {
            ws[EW1 + eb] = s1[0] + s1[1] + s1[2] + s1[3];
            ws[EW2 + eb] = s2[0] + s2[1] + s2[2] + s2[3];
        }
        return;
    }

    // ---------------- chamfer via MFMA ----------------
    int dir = bid / (NBT * NQC);
    int rem = bid % (NBT * NQC);
    int bt = rem / NQC;
    int qc = rem % NQC;
    const float* P = dir ? TP : OP;      // queries
    const float* Q = dir ? OP : TP;      // references
    const float* Pb = P + (size_t)bt * NPTS * 3;
    const float* Qb = Q + (size_t)bt * NPTS * 3;

    // A fragment: row = lane&31 -> query; k=(lane>>5)*8+i; data only in k=0..3
    // Lanes >=32 (k=8..15) are ZERO in A, which makes B's k>=4 slots don't-care.
    int qrow = lane & 31;
    int qidx = qc * QPB + wave * 32 + qrow;
    float qx = 0.0f, qy = 0.0f, qz = 0.0f;
    if (lane < 32) {
        const float* p = Pb + (size_t)qidx * 3;
        qx = p[0]; qy = p[1]; qz = p[2];
        nqlds[wave][qrow] = fmaf(qx, qx, fmaf(qy, qy, qz * qz));
    }
    union { unsigned u[4]; h8 h; } ua;
    ua.u[0] = ua.u[1] = ua.u[2] = ua.u[3] = 0u;
    if (lane < 32) {
        ua.u[0] = pkh(-2.0f * qx, -2.0f * qy);
        ua.u[1] = pkh(-2.0f * qz, 1.0f);
    }
    h8 afrag = ua.h;

    const f32x16 zc = {0.0f, 0.0f, 0.0f, 0.0f, 0.0f, 0.0f, 0.0f, 0.0f,
                       0.0f, 0.0f, 0.0f, 0.0f, 0.0f, 0.0f, 0.0f, 0.0f};
    float vm[16];
#pragma unroll
    for (int r = 0; r < 16; ++r) vm[r] = INFINITY;

    // stage tile t (CT points) as f16 (x,y | z,n); 4 points per thread
#define STAGE(t, b)                                                          \
    {                                                                        \
        int pt0 = (t) * CT + tid * 4;                                        \
        const f32x4* src = (const f32x4*)(Qb + (size_t)pt0 * 3);             \
        f32x4 c0 = src[0], c1 = src[1], c2 = src[2];                         \
        float x0 = c0[0], y0 = c0[1], z0 = c0[2];                            \
        float x1 = c0[3], y1 = c1[0], z1 = c1[1];                            \
        float x2 = c1[2], y2 = c1[3], z2 = c2[0];                            \
        float x3 = c2[1], y3 = c2[2], z3 = c2[3];                            \
        float n0 = fmaf(x0, x0, fmaf(y0, y0, z0 * z0));                      \
        float n1 = fmaf(x1, x1, fmaf(y1, y1, z1 * z1));                      \
        float n2 = fmaf(x2, x2, fmaf(y2, y2, z2 * z2));                      \
        float n3 = fmaf(x3, x3, fmaf(y3, y3, z3 * z3));                      \
        uint4* dst = (uint4*)&pts[b][tid * 4];                               \
        dst[0] = make_uint4(pkh(x0, y0), pkh(z0, n0), pkh(x1, y1), pkh(z1, n1)); \
        dst[1] = make_uint4(pkh(x2, y2), pkh(z2, n2), pkh(x3, y3), pkh(z3, n3)); \
    }

    STAGE(0, 0);
    __syncthreads();
    for (int t = 0; t < NT; ++t) {
        if (t + 1 < NT) STAGE(t + 1, (t + 1) & 1);
        const uint2* pb = pts[t & 1];
#pragma unroll
        for (int g = 0; g < CT / 128; ++g) {   // 4 point-subtiles of 32 per group
            uint2 b0 = pb[g * 128 + 0 * 32 + qrow];   // lanes>=32: same addr, broadcast
            uint2 b1 = pb[g * 128 + 1 * 32 + qrow];
            uint2 b2 = pb[g * 128 + 2 * 32 + qrow];
            uint2 b3 = pb[g * 128 + 3 * 32 + qrow];
            union { unsigned u[4]; h8 h; } ub0, ub1, ub2, ub3;
            ub0.u[0] = b0.x; ub0.u[1] = b0.y; ub0.u[2] = 0u; ub0.u[3] = 0u;
            ub1.u[0] = b1.x; ub1.u[1] = b1.y; ub1.u[2] = 0u; ub1.u[3] = 0u;
            ub2.u[0] = b2.x; ub2.u[1] = b2.y; ub2.u[2] = 0u; ub2.u[3] = 0u;
            ub3.u[0] = b3.x; ub3.u[1] = b3.y; ub3.u[2] = 0u; ub3.u[3] = 0u;
            f32x16 d0 = __builtin_amdgcn_mfma_f32_32x32x16_f16(afrag, ub0.h, zc, 0, 0, 0);
            f32x16 d1 = __builtin_amdgcn_mfma_f32_32x32x16_f16(afrag, ub1.h, zc, 0, 0, 0);
            f32x16 d2 = __builtin_amdgcn_mfma_f32_32x32x16_f16(afrag, ub2.h, zc, 0, 0, 0);
            f32x16 d3 = __builtin_amdgcn_mfma_f32_32x32x16_f16(afrag, ub3.h, zc, 0, 0, 0);
#pragma unroll
            for (int r = 0; r < 16; ++r) {
                float a = d0[r], c = d1[r];
                asm("v_min3_f32 %0, %0, %1, %2" : "+v"(vm[r]) : "v"(a), "v"(c));
            }
#pragma unroll
            for (int r = 0; r < 16; ++r) {
                float a = d2[r], c = d3[r];
                asm("v_min3_f32 %0, %0, %1, %2" : "+v"(vm[r]) : "v"(a), "v"(c));
            }
        }
        __syncthreads();
    }

    // min across the 32 lanes of each half (cols); rows live in regs
#pragma unroll
    for (int r = 0; r < 16; ++r) {
        float m = vm[r];
        m = fminf(m, __shfl_xor(m, 1));
        m = fminf(m, __shfl_xor(m, 2));
        m = fminf(m, __shfl_xor(m, 4));
        m = fminf(m, __shfl_xor(m, 8));
        m = fminf(m, __shfl_xor(m, 16));
        vm[r] = m;
    }
    float part = 0.0f;
    if ((lane & 31) == 0) {   // lanes 0 and 32 hold the 2 row-sets
        int half = lane >> 5;
#pragma unroll
        for (int r = 0; r < 16; ++r) {
            int row = (r & 3) + 8 * (r >> 2) + 4 * half;
            part += vm[r] + nqlds[wave][row];
        }
    }
    part += __shfl_xor(part, 32);
    if (lane == 0) ws[bid * 4 + wave] = part;
}

__global__ void finalize_kernel(const float* __restrict__ ws, float* __restrict__ out) {
    __shared__ float grp[20];
    __shared__ float ra[4], rb[4];
    int tid = threadIdx.x;
    int lane = tid & 63;
    int wave = tid >> 6;

    // chamfer partials: 20 groups (dir*10+bt) of 128
    for (int g = wave; g < 20; g += 4) {
        float s = 0.0f;
        for (int j = lane; j < 128; j += 64) s += ws[g * 128 + j];
#pragma unroll
        for (int off = 32; off > 0; off >>= 1) s += __shfl_down(s, off);
        if (lane == 0) grp[g] = s;
    }

    // ew partials: 640 each
    float sa = 0.0f, sb = 0.0f;
    for (int i = tid; i < EW_BLOCKS; i += 256) {
        sa += ws[EW1 + i];
        sb += ws[EW2 + i];
    }
#pragma unroll
    for (int off = 32; off > 0; off >>= 1) {
        sa += __shfl_down(sa, off);
        sb += __shfl_down(sb, off);
    }
    if (lane == 0) { ra[wave] = sa; rb[wave] = sb; }
    __syncthreads();

    if (tid == 0) {
        const float inv_e = 1.0f / (float)NELEM;
        float loss_rv = (ra[0] + ra[1] + ra[2] + ra[3]) * inv_e;
        float loss_mask = (rb[0] + rb[1] + rb[2] + rb[3]) * inv_e;
        float cd_sum = 0.0f;
        for (int bt = 0; bt < NBT; ++bt) {
            float cd = (grp[bt] + grp[NBT + bt]) * (1.0f / NPTS);
            int b = bt / TT;
            int t = bt % TT;
            out[1 + t * BB + b] = cd;   // cd_tensor is [T,B]
            cd_sum += cd;
        }
        float loss_cd = cd_sum / (float)NBT;
        out[0] = loss_cd + loss_rv + loss_mask;  // weights all 1.0
        out[11] = loss_cd;
        out[12] = loss_rv;
        out[13] = loss_mask;
    }
}

extern "C" void kernel_launch(void* const* d_in, const int* in_sizes, int n_in,
                              void* d_out, int out_size, void* d_ws, size_t ws_size,
                              hipStream_t stream) {
    const float* output_rv = (const float*)d_in[0];
    const float* mask_logits = (const float*)d_in[1];
    const float* output_points = (const float*)d_in[2];
    const float* target_points = (const float*)d_in[3];
    const float* target_rv = (const float*)d_in[4];
    float* out = (float*)d_out;
    float* ws = (float*)d_ws;

    main_kernel<<<CH_BLOCKS + EW_BLOCKS, 256, 0, stream>>>(
        (const float4*)output_rv, (const float4*)mask_logits,
        (const float4*)target_rv, output_points, target_points, ws);

    finalize_kernel<<<1, 256, 0, stream>>>(ws, out);
}